// Round 8
// baseline (409.665 us; speedup 1.0000x reference)
//
#include <hip/hip_runtime.h>
#include <stdint.h>
#include <stddef.h>

// BitLinear on MI355X: out[m,o] = sx[m] * sw * sum_i qx[m,i]*qw[o,i]
//   qx: per-row int8 absmax fake-quant of x, qw: ternary {-1,0,1} from absmean.
// Integer inner product is exact; only scales carry float rounding.

#define K_DIM 4096
#define M_DIM 8192
#define N_DIM 4096

typedef int v4i  __attribute__((ext_vector_type(4)));
typedef int v16i __attribute__((ext_vector_type(16)));

// ---------------- async global->LDS (16B per lane, wave-uniform LDS base) ----
__device__ __forceinline__ void async_copy16(void* lds, const void* g) {
  __builtin_amdgcn_global_load_lds(
      (const __attribute__((address_space(1))) unsigned int*)g,
      (__attribute__((address_space(3))) unsigned int*)lds,
      16, 0, 0);
}

// ---------------- kernel 1: per-block partial sums of |w| (double) ----------
__global__ void k_wsum(const float* __restrict__ w, double* __restrict__ partials) {
  const float4* w4 = (const float4*)w;
  int tid = blockIdx.x * 256 + threadIdx.x;          // 262144 threads
  double s = 0.0;
  for (int i = tid; i < 4194304; i += 262144) {      // 16 iters
    float4 v = w4[i];
    s += (double)fabsf(v.x) + (double)fabsf(v.y) +
         (double)fabsf(v.z) + (double)fabsf(v.w);
  }
  for (int off = 32; off > 0; off >>= 1) s += __shfl_down(s, off);
  __shared__ double lsum[4];
  int lane = threadIdx.x & 63, wid = threadIdx.x >> 6;
  if (lane == 0) lsum[wid] = s;
  __syncthreads();
  if (threadIdx.x == 0)
    partials[blockIdx.x] = lsum[0] + lsum[1] + lsum[2] + lsum[3];
}

// ---------------- kernel 2: FUSED quantization (w-ternary + x-int8) ---------
// Blocks 0..2047 = wq path (exact threshold compare, bitwise-identical to
// rint(w/d) clipped; see R5 notes). Blocks 2048..10239 = xq path.
__global__ void k_quant(const float* __restrict__ w, const double* __restrict__ partials,
                        float* __restrict__ wscale, char* __restrict__ qw,
                        const float* __restrict__ x, char* __restrict__ qx,
                        float* __restrict__ sx) {
  __shared__ float sT;
  __shared__ float lm[4];
  __shared__ float bscale;

  if (blockIdx.x < 2048) {
    // ---------------- w ternary-quant path ----------------
    if (threadIdx.x < 64) {
      double s = 0.0;
      for (int i = threadIdx.x; i < 1024; i += 64) s += partials[i];
      for (int off = 32; off > 0; off >>= 1) s += __shfl_down(s, off);
      if (threadIdx.x == 0) {
        float sc = (float)(s / 16777216.0);          // mean(|w|)
        if (blockIdx.x == 0) *wscale = sc;           // for the GEMM epilogue
        float d = sc + 1e-8f;                        // matches ref divisor
        unsigned lo = 1u, hi = __float_as_uint(d);   // pred(t) = t/d > 0.5f
        while (hi - lo > 1u) {
          unsigned mid = lo + ((hi - lo) >> 1);
          if (__uint_as_float(mid) / d > 0.5f) hi = mid; else lo = mid;
        }
        sT = __uint_as_float(hi);                    // smallest t with pred
      }
    }
    __syncthreads();
    const float T = sT;
    const float4* w4 = (const float4*)w;
    int* q4 = (int*)qw;
    int tid = blockIdx.x * 256 + threadIdx.x;        // 524288 threads on w
    for (int i = tid; i < 4194304; i += 524288) {    // 8 iters
      float4 v = w4[i];
      int a = (int)(v.x >= T) - (int)(v.x <= -T);
      int b = (int)(v.y >= T) - (int)(v.y <= -T);
      int c = (int)(v.z >= T) - (int)(v.z <= -T);
      int e = (int)(v.w >= T) - (int)(v.w <= -T);
      q4[i] = (a & 255) | ((b & 255) << 8) | ((c & 255) << 16) | ((e & 255) << 24);
    }
  } else {
    // ---------------- x per-row int8 absmax path ----------------
    int row = blockIdx.x - 2048;                     // 8192 rows
    const float4* xr = (const float4*)(x + (size_t)row * K_DIM);
    float4 v[4];
    float m = 0.f;
#pragma unroll
    for (int c = 0; c < 4; c++) {
      v[c] = xr[threadIdx.x + c * 256];
      m = fmaxf(m, fmaxf(fmaxf(fabsf(v[c].x), fabsf(v[c].y)),
                         fmaxf(fabsf(v[c].z), fabsf(v[c].w))));
    }
    for (int off = 32; off > 0; off >>= 1) m = fmaxf(m, __shfl_down(m, off));
    int lane = threadIdx.x & 63, wid = threadIdx.x >> 6;
    if (lane == 0) lm[wid] = m;
    __syncthreads();
    if (threadIdx.x == 0) {
      float mm = fmaxf(fmaxf(lm[0], lm[1]), fmaxf(lm[2], lm[3]));
      float sc = fmaxf(mm / 127.0f, 1e-8f);          // true division like ref
      bscale = sc;
      sx[row] = sc;
    }
    __syncthreads();
    float sc = bscale;
    int* q4 = (int*)(qx + (size_t)row * K_DIM);
#pragma unroll
    for (int c = 0; c < 4; c++) {
      int a = (int)fmaxf(fminf(rintf(v[c].x / sc), 127.f), -127.f);
      int b = (int)fmaxf(fminf(rintf(v[c].y / sc), 127.f), -127.f);
      int cc = (int)fmaxf(fminf(rintf(v[c].z / sc), 127.f), -127.f);
      int e = (int)fmaxf(fminf(rintf(v[c].w / sc), 127.f), -127.f);
      q4[threadIdx.x + c * 256] = (a & 255) | ((b & 255) << 8) | ((cc & 255) << 16) | ((e & 255) << 24);
    }
  }
}

// ---------------- kernel 4: int8 MFMA GEMM, 256x256 tile, 32x32x32 shape ----
// R8: same proven skeleton as R1/R3 (4 circular buffers, depth-3 DMA, ONE
// barrier per tile, counted vmcnt never 0 in main loop, T2 both-sides XOR
// swizzle, XCD-aware block swizzle) but the wave's 128x64 output is computed
// with 16x v_mfma_i32_32x32x32_i8 per K-tile instead of 32x 16x16x64:
//   - 32x32 i8 pipe is 11.6% faster than 16x16 (4404 vs 3944 TOPS ubench)
//   - half the MFMA issue slots, half the acc-init instructions
//   - identical LDS bytes; 32-row column-slice reads remain conflict-free
//     under the same XOR involution (uniform 8 accesses/bank = wave minimum)
// A-frag (32x32,K=32): row=lane&31, 16 contiguous k-bytes at (lane>>5)*16.
// C/D: col=lane&31, row=(reg&3)+8*(reg>>2)+4*(lane>>5), reg in [0,16).
// Refuted & closed: R2 fine phase-split (163us), R4 2-tile windows (161us),
// R6 B-only LDS / global-A (215us), R3 reg pre-read (neutral).
__global__ __launch_bounds__(512, 2) void k_gemm(const char* __restrict__ qx,
                       const char* __restrict__ qw,
                       const float* __restrict__ sx,
                       const float* __restrict__ wscale,
                       float* __restrict__ out) {
  __shared__ char lds[4][32768];                 // [buf][A:0..16K | B:16K..32K]

  const int tid = threadIdx.x;
  const int lane = tid & 63;
  const int wave = tid >> 6;                     // 0..7
  const int wr = wave >> 2;                      // M-half 0/1   (128 rows)
  const int wc = wave & 3;                       // N-quarter 0..3 (64 cols)

  // XCD-aware bijective swizzle (512 wgs, 8 XCDs, 64 wgs per XCD chunk)
  const int wg = (blockIdx.x & 7) * 64 + (blockIdx.x >> 3);
  const int bm = wg >> 4;                        // 32 M-tiles
  const int bn = wg & 15;                        // 16 N-tiles
  const int rowBase = bm * 256;
  const int colBase = bn * 256;

  // ---- staging addressing: LDS linear (tid*16), global source pre-swizzled
  const int rl = tid >> 2;                       // row 0..127 within half-tile
  const int kswz = (((tid & 3) ^ ((rl >> 1) & 3)) << 4);
  const char* gA0 = qx + (size_t)(rowBase + rl) * K_DIM + kswz;
  const char* gA1 = gA0 + (size_t)128 * K_DIM;   // rows 128..255 (same swizzle)
  const char* gB0 = qw + (size_t)(colBase + rl) * K_DIM + kswz;
  const char* gB1 = gB0 + (size_t)128 * K_DIM;
  const int dOff = wave << 10;                   // wave-uniform LDS base

  // ---- compute-phase read offsets (same XOR involution on the k16 column)
  // lane reads row (lane&31) of its 32-row subtile; k16 column for MFMA
  // k-step kk is (2*kk + (lane>>5)), XORed with sel = (row>>1)&3 = (lane>>1)&3.
  const int hi = lane >> 5;
  const int selk = (lane >> 1) & 3;
  const int colk[2] = { ((hi) ^ selk) << 4, ((2 + hi) ^ selk) << 4 };
  const int aBase = ((wr << 7) + (lane & 31)) * 64;           // + sub*2048
  const int bBase = 16384 + ((wc << 6) + (lane & 31)) * 64;   // + sn*2048

  v16i acc[4][2] = {};                           // 4 M-subtiles x 2 N-subtiles

  auto STAGE = [&](int t) {
    char* b = &lds[t & 3][0];
    const size_t ko = (size_t)t << 6;            // t*64 bytes along K
    async_copy16(b + dOff,         gA0 + ko);    // A rows   0..127
    async_copy16(b + 8192 + dOff,  gA1 + ko);    // A rows 128..255
    async_copy16(b + 16384 + dOff, gB0 + ko);    // B rows   0..127
    async_copy16(b + 24576 + dOff, gB1 + ko);    // B rows 128..255
  };

  auto BODY = [&](int t, bool doStage) {
    const char* b_ = &lds[t & 3][0];
    v4i bv[2][2], av[4][2];
#pragma unroll
    for (int sn = 0; sn < 2; ++sn)
#pragma unroll
      for (int kk = 0; kk < 2; ++kk)
        bv[sn][kk] = *(const v4i*)(b_ + bBase + sn * 2048 + colk[kk]);
#pragma unroll
    for (int sub = 0; sub < 4; ++sub)
#pragma unroll
      for (int kk = 0; kk < 2; ++kk)
        av[sub][kk] = *(const v4i*)(b_ + aBase + sub * 2048 + colk[kk]);
    if (doStage) STAGE(t + 3);
    asm volatile("" ::: "memory");
    __builtin_amdgcn_s_setprio(1);
#pragma unroll
    for (int kk = 0; kk < 2; ++kk)
#pragma unroll
      for (int sub = 0; sub < 4; ++sub)
#pragma unroll
        for (int sn = 0; sn < 2; ++sn)
          acc[sub][sn] = __builtin_amdgcn_mfma_i32_32x32x32_i8(
              av[sub][kk], bv[sn][kk], acc[sub][sn], 0, 0, 0);
    __builtin_amdgcn_s_setprio(0);
  };

  // prologue: 3 tiles in flight (12 per-wave loads)
  STAGE(0); STAGE(1); STAGE(2);

  // main loop: 61 iters, stages 3..63, vmcnt never below 8
  for (int t = 0; t < 61; ++t) {
    asm volatile("s_waitcnt vmcnt(8)" ::: "memory");   // tile t landed
    __builtin_amdgcn_s_barrier();                      // publish tile t
    asm volatile("" ::: "memory");
    BODY(t, true);
  }
  // tail: tiles 61,62,63 -- no staging, drain 8 -> 4 -> 0
  asm volatile("s_waitcnt vmcnt(8)" ::: "memory");
  __builtin_amdgcn_s_barrier();
  asm volatile("" ::: "memory");
  BODY(61, false);
  asm volatile("s_waitcnt vmcnt(4)" ::: "memory");
  __builtin_amdgcn_s_barrier();
  asm volatile("" ::: "memory");
  BODY(62, false);
  asm volatile("s_waitcnt vmcnt(0)" ::: "memory");
  __builtin_amdgcn_s_barrier();
  asm volatile("" ::: "memory");
  BODY(63, false);

  // epilogue: 32x32 C/D layout col=lane&31, row=(reg&3)+8*(reg>>2)+4*hi
  const float swv = *wscale;
  const int colE = colBase + (wc << 6) + (lane & 31);
#pragma unroll
  for (int sub = 0; sub < 4; ++sub) {
#pragma unroll
    for (int reg = 0; reg < 16; ++reg) {
      const int row = rowBase + (wr << 7) + sub * 32 + 4 * hi +
                      (reg & 3) + 8 * (reg >> 2);
      const float s = sx[row] * swv;
#pragma unroll
      for (int sn = 0; sn < 2; ++sn)
        out[(size_t)row * N_DIM + colE + sn * 32] = (float)acc[sub][sn][reg] * s;
    }
  }
}

// ---------------- launcher ---------------------------------------------------
extern "C" void kernel_launch(void* const* d_in, const int* in_sizes, int n_in,
                              void* d_out, int out_size, void* d_ws, size_t ws_size,
                              hipStream_t stream) {
  const float* x = (const float*)d_in[0];   // [2,4096,4096]
  const float* w = (const float*)d_in[1];   // [4096,4096]
  float* out = (float*)d_out;               // [2,4096,4096]
  char* ws = (char*)d_ws;

  // ws layout (needs ~48.1 MiB):
  double* partials = (double*)ws;                  // 1024 doubles  @ 0
  float* wscale    = (float*)(ws + 8192);          // 1 float       @ 8192
  float* sx        = (float*)(ws + 8448);          // 8192 floats   @ 8448
  char*  qw        = ws + 41472;                   // 16 MiB        @ 41472
  char*  qx        = ws + 41472 + 16777216;        // 32 MiB

  k_wsum <<<1024, 256, 0, stream>>>(w, partials);
  k_quant<<<2048 + 8192, 256, 0, stream>>>(w, partials, wscale, qw, x, qx, sx);
  k_gemm <<<32 * 16, 512, 0, stream>>>(qx, qw, sx, wscale, out);
}

// Round 9
// 402.372 us; speedup vs baseline: 1.0181x; 1.0181x over previous
//
#include <hip/hip_runtime.h>
#include <stdint.h>
#include <stddef.h>

// BitLinear on MI355X: out[m,o] = sx[m] * sw * sum_i qx[m,i]*qw[o,i]
//   qx: per-row int8 absmax fake-quant of x, qw: ternary {-1,0,1} from absmean.
// Integer inner product is exact; only scales carry float rounding.

#define K_DIM 4096
#define M_DIM 8192
#define N_DIM 4096

typedef int v4i __attribute__((ext_vector_type(4)));

// ---------------- async global->LDS (16B per lane, wave-uniform LDS base) ----
__device__ __forceinline__ void async_copy16(void* lds, const void* g) {
  __builtin_amdgcn_global_load_lds(
      (const __attribute__((address_space(1))) unsigned int*)g,
      (__attribute__((address_space(3))) unsigned int*)lds,
      16, 0, 0);
}

// ---------------- kernel 1: per-block partial sums of |w| (double) ----------
__global__ void k_wsum(const float* __restrict__ w, double* __restrict__ partials) {
  const float4* w4 = (const float4*)w;
  int tid = blockIdx.x * 256 + threadIdx.x;          // 262144 threads
  double s = 0.0;
  for (int i = tid; i < 4194304; i += 262144) {      // 16 iters
    float4 v = w4[i];
    s += (double)fabsf(v.x) + (double)fabsf(v.y) +
         (double)fabsf(v.z) + (double)fabsf(v.w);
  }
  for (int off = 32; off > 0; off >>= 1) s += __shfl_down(s, off);
  __shared__ double lsum[4];
  int lane = threadIdx.x & 63, wid = threadIdx.x >> 6;
  if (lane == 0) lsum[wid] = s;
  __syncthreads();
  if (threadIdx.x == 0)
    partials[blockIdx.x] = lsum[0] + lsum[1] + lsum[2] + lsum[3];
}

// ---------------- kernel 2: FUSED quantization (w-ternary + x-int8) ---------
// Blocks 0..2047 = wq path (exact threshold compare, bitwise-identical to
// rint(w/d) clipped; see R5 notes). Blocks 2048..10239 = xq path.
__global__ void k_quant(const float* __restrict__ w, const double* __restrict__ partials,
                        float* __restrict__ wscale, char* __restrict__ qw,
                        const float* __restrict__ x, char* __restrict__ qx,
                        float* __restrict__ sx) {
  __shared__ float sT;
  __shared__ float lm[4];
  __shared__ float bscale;

  if (blockIdx.x < 2048) {
    // ---------------- w ternary-quant path ----------------
    if (threadIdx.x < 64) {
      double s = 0.0;
      for (int i = threadIdx.x; i < 1024; i += 64) s += partials[i];
      for (int off = 32; off > 0; off >>= 1) s += __shfl_down(s, off);
      if (threadIdx.x == 0) {
        float sc = (float)(s / 16777216.0);          // mean(|w|)
        if (blockIdx.x == 0) *wscale = sc;           // for the GEMM epilogue
        float d = sc + 1e-8f;                        // matches ref divisor
        unsigned lo = 1u, hi = __float_as_uint(d);   // pred(t) = t/d > 0.5f
        while (hi - lo > 1u) {
          unsigned mid = lo + ((hi - lo) >> 1);
          if (__uint_as_float(mid) / d > 0.5f) hi = mid; else lo = mid;
        }
        sT = __uint_as_float(hi);                    // smallest t with pred
      }
    }
    __syncthreads();
    const float T = sT;
    const float4* w4 = (const float4*)w;
    int* q4 = (int*)qw;
    int tid = blockIdx.x * 256 + threadIdx.x;        // 524288 threads on w
    for (int i = tid; i < 4194304; i += 524288) {    // 8 iters
      float4 v = w4[i];
      int a = (int)(v.x >= T) - (int)(v.x <= -T);
      int b = (int)(v.y >= T) - (int)(v.y <= -T);
      int c = (int)(v.z >= T) - (int)(v.z <= -T);
      int e = (int)(v.w >= T) - (int)(v.w <= -T);
      q4[i] = (a & 255) | ((b & 255) << 8) | ((c & 255) << 16) | ((e & 255) << 24);
    }
  } else {
    // ---------------- x per-row int8 absmax path ----------------
    int row = blockIdx.x - 2048;                     // 8192 rows
    const float4* xr = (const float4*)(x + (size_t)row * K_DIM);
    float4 v[4];
    float m = 0.f;
#pragma unroll
    for (int c = 0; c < 4; c++) {
      v[c] = xr[threadIdx.x + c * 256];
      m = fmaxf(m, fmaxf(fmaxf(fabsf(v[c].x), fabsf(v[c].y)),
                         fmaxf(fabsf(v[c].z), fabsf(v[c].w))));
    }
    for (int off = 32; off > 0; off >>= 1) m = fmaxf(m, __shfl_down(m, off));
    int lane = threadIdx.x & 63, wid = threadIdx.x >> 6;
    if (lane == 0) lm[wid] = m;
    __syncthreads();
    if (threadIdx.x == 0) {
      float mm = fmaxf(fmaxf(lm[0], lm[1]), fmaxf(lm[2], lm[3]));
      float sc = fmaxf(mm / 127.0f, 1e-8f);          // true division like ref
      bscale = sc;
      sx[row] = sc;
    }
    __syncthreads();
    float sc = bscale;
    int* q4 = (int*)(qx + (size_t)row * K_DIM);
#pragma unroll
    for (int c = 0; c < 4; c++) {
      int a = (int)fmaxf(fminf(rintf(v[c].x / sc), 127.f), -127.f);
      int b = (int)fmaxf(fminf(rintf(v[c].y / sc), 127.f), -127.f);
      int cc = (int)fmaxf(fminf(rintf(v[c].z / sc), 127.f), -127.f);
      int e = (int)fmaxf(fminf(rintf(v[c].w / sc), 127.f), -127.f);
      q4[threadIdx.x + c * 256] = (a & 255) | ((b & 255) << 8) | ((cc & 255) << 16) | ((e & 255) << 24);
    }
  }
}

// ---------------- kernel 4: int8 MFMA GEMM, 256x256 tile, 16-MFMA phases ----
// R9: faithful T3 port per the m201 template onto the PROVEN R1/R3 layout
// (4 circular buffers, depth-3 staging, T2 both-sides XOR swizzle, T1 XCD
// swizzle, T5 setprio, vmcnt(8) per tile -- never 0 in main loop).
// Each 32-MFMA K-tile splits into TWO 16-MFMA phases (m201's phase size;
// R2's 8-MFMA phases were the catalog-predicted-failure variant):
//   publish: vmcnt(8); s_barrier            -- buf[t&3] visible to all
//   phase A: ds_read A0-3,B0-3 (8xb128) ; stage 2 A-halves of tile t+3
//            s_barrier ; 16 MFMA (m0-3 x n0-3, setprio-wrapped) ; s_barrier
//   phase B: ds_read A4-7 (4xb128, B REUSED in regs) ; stage 2 B-halves
//            s_barrier ; 16 MFMA (m4-7 x n0-3)
// ds_reads are compiler-visible -> it emits fine-grained counted lgkmcnt
// (no drain). Race-freedom identical to R1: all waves' reads of buf[(t-1)&3]
// are consumed before the publish barrier of tile t; STAGE(t+3) writes that
// buffer only after it. vmcnt(8) covers tile t's 4 loads (issued 3 tiles,
// ~7600cyc, earlier); 8 loads (t+1,t+2) stay in flight.
// Refuted & closed: R2 8-MFMA-phase split (163us), R4 2-tile windows (161us),
// R6 B-only LDS/global-A (215us), R8 32x32x32 shape (160us, 12.6M conflicts),
// R3 reg pre-read (neutral).
__global__ __launch_bounds__(512, 2) void k_gemm(const char* __restrict__ qx,
                       const char* __restrict__ qw,
                       const float* __restrict__ sx,
                       const float* __restrict__ wscale,
                       float* __restrict__ out) {
  __shared__ char lds[4][32768];                 // [buf][A:0..16K | B:16K..32K]

  const int tid = threadIdx.x;
  const int lane = tid & 63;
  const int wave = tid >> 6;                     // 0..7
  const int wr = wave >> 2;                      // M-half 0/1
  const int wc = wave & 3;                       // N-quarter 0..3

  // XCD-aware bijective swizzle (512 wgs, 8 XCDs, 64 wgs per XCD chunk)
  const int wg = (blockIdx.x & 7) * 64 + (blockIdx.x >> 3);
  const int bm = wg >> 4;                        // 32 M-tiles
  const int bn = wg & 15;                        // 16 N-tiles
  const int rowBase = bm * 256;
  const int colBase = bn * 256;

  // ---- staging addressing: LDS linear (tid*16), global source pre-swizzled
  const int rl = tid >> 2;                       // row 0..127 within half-tile
  const int kswz = (((tid & 3) ^ ((rl >> 1) & 3)) << 4);
  const char* gA0 = qx + (size_t)(rowBase + rl) * K_DIM + kswz;
  const char* gA1 = gA0 + (size_t)128 * K_DIM;   // rows 128..255 (same swizzle)
  const char* gB0 = qw + (size_t)(colBase + rl) * K_DIM + kswz;
  const char* gB1 = gB0 + (size_t)128 * K_DIM;
  const int dOff = wave << 10;                   // wave-uniform LDS base

  // ---- compute-phase read offsets (same XOR involution on the k16 column)
  const int sR = ((lane & 15) >> 1) & 3;
  const int kro = (((lane >> 4) ^ sR) << 4);
  const int aOff = ((wr << 7) + (lane & 15)) * 64 + kro;          // A region
  const int bOff = 16384 + ((wc << 6) + (lane & 15)) * 64 + kro;  // B region

  v4i acc[8][4] = {};

  auto STAGE = [&](int t) {                      // prologue only: all 4 loads
    char* b = &lds[t & 3][0];
    const size_t ko = (size_t)t << 6;
    async_copy16(b + dOff,         gA0 + ko);
    async_copy16(b + 8192 + dOff,  gA1 + ko);
    async_copy16(b + 16384 + dOff, gB0 + ko);
    async_copy16(b + 24576 + dOff, gB1 + ko);
  };

  // two 16-MFMA phases for tile t; stages tile t+3 (A-halves in phase A,
  // B-halves in phase B) when doStage is set
  auto PHASES = [&](int t, bool doStage) {
    const char* b_ = &lds[t & 3][0];
    char* sb_ = &lds[(t + 3) & 3][0];
    const size_t ko_ = (size_t)(t + 3) << 6;
    // ---- phase A: reads + A-half staging
    v4i bf[4], a0[4];
#pragma unroll
    for (int n = 0; n < 4; ++n)
      bf[n] = *(const v4i*)(b_ + bOff + n * 1024);
#pragma unroll
    for (int j = 0; j < 4; ++j)
      a0[j] = *(const v4i*)(b_ + aOff + j * 1024);
    if (doStage) {
      async_copy16(sb_ + dOff,        gA0 + ko_);
      async_copy16(sb_ + 8192 + dOff, gA1 + ko_);
    }
    asm volatile("" ::: "memory");
    __builtin_amdgcn_s_barrier();                // A-mid
    __builtin_amdgcn_s_setprio(1);
#pragma unroll
    for (int m = 0; m < 4; ++m)
#pragma unroll
      for (int n = 0; n < 4; ++n)
        acc[m][n] = __builtin_amdgcn_mfma_i32_16x16x64_i8(a0[m], bf[n], acc[m][n], 0, 0, 0);
    __builtin_amdgcn_s_setprio(0);
    asm volatile("" ::: "memory");
    __builtin_amdgcn_s_barrier();                // A-trail
    // ---- phase B: reads (B reused) + B-half staging
    v4i a1[4];
#pragma unroll
    for (int j = 0; j < 4; ++j)
      a1[j] = *(const v4i*)(b_ + aOff + (4 + j) * 1024);
    if (doStage) {
      async_copy16(sb_ + 16384 + dOff, gB0 + ko_);
      async_copy16(sb_ + 24576 + dOff, gB1 + ko_);
    }
    asm volatile("" ::: "memory");
    __builtin_amdgcn_s_barrier();                // B-mid
    __builtin_amdgcn_s_setprio(1);
#pragma unroll
    for (int m = 0; m < 4; ++m)
#pragma unroll
      for (int n = 0; n < 4; ++n)
        acc[4 + m][n] = __builtin_amdgcn_mfma_i32_16x16x64_i8(a1[m], bf[n], acc[4 + m][n], 0, 0, 0);
    __builtin_amdgcn_s_setprio(0);
  };

  // prologue: 3 tiles in flight (12 per-wave loads)
  STAGE(0); STAGE(1); STAGE(2);

  // main loop: 61 tiles with staging
  for (int t = 0; t < 61; ++t) {
    asm volatile("s_waitcnt vmcnt(8)" ::: "memory");   // tile t landed
    __builtin_amdgcn_s_barrier();                      // publish
    asm volatile("" ::: "memory");
    PHASES(t, true);
  }
  // tail: tiles 61,62,63 -- no staging, drain 8 -> 4 -> 0
  asm volatile("s_waitcnt vmcnt(8)" ::: "memory");
  __builtin_amdgcn_s_barrier();
  asm volatile("" ::: "memory");
  PHASES(61, false);
  asm volatile("s_waitcnt vmcnt(4)" ::: "memory");
  __builtin_amdgcn_s_barrier();
  asm volatile("" ::: "memory");
  PHASES(62, false);
  asm volatile("s_waitcnt vmcnt(0)" ::: "memory");
  __builtin_amdgcn_s_barrier();
  asm volatile("" ::: "memory");
  PHASES(63, false);

  // epilogue: C/D 16x16 layout col=lane&15, row=(lane>>4)*4+reg
  const float swv = *wscale;
  const int col0 = colBase + (wc << 6) + (lane & 15);
  const int row0 = rowBase + (wr << 7) + ((lane >> 4) << 2);
#pragma unroll
  for (int m = 0; m < 8; ++m) {
#pragma unroll
    for (int r = 0; r < 4; ++r) {
      const int row = row0 + m * 16 + r;
      const float s = sx[row] * swv;
#pragma unroll
      for (int n = 0; n < 4; ++n)
        out[(size_t)row * N_DIM + col0 + n * 16] = (float)acc[m][n][r] * s;
    }
  }
}

// ---------------- launcher ---------------------------------------------------
extern "C" void kernel_launch(void* const* d_in, const int* in_sizes, int n_in,
                              void* d_out, int out_size, void* d_ws, size_t ws_size,
                              hipStream_t stream) {
  const float* x = (const float*)d_in[0];   // [2,4096,4096]
  const float* w = (const float*)d_in[1];   // [4096,4096]
  float* out = (float*)d_out;               // [2,4096,4096]
  char* ws = (char*)d_ws;

  // ws layout (needs ~48.1 MiB):
  double* partials = (double*)ws;                  // 1024 doubles  @ 0
  float* wscale    = (float*)(ws + 8192);          // 1 float       @ 8192
  float* sx        = (float*)(ws + 8448);          // 8192 floats   @ 8448
  char*  qw        = ws + 41472;                   // 16 MiB        @ 41472
  char*  qx        = ws + 41472 + 16777216;        // 32 MiB

  k_wsum <<<1024, 256, 0, stream>>>(w, partials);
  k_quant<<<2048 + 8192, 256, 0, stream>>>(w, partials, wscale, qw, x, qx, sx);
  k_gemm <<<32 * 16, 512, 0, stream>>>(qx, qw, sx, wscale, out);
}